// Round 1
// baseline (874.957 us; speedup 1.0000x reference)
//
#include <hip/hip_runtime.h>

#define B_ 32
#define N_ 1000
#define K_ 10
#define H_ 128
#define C_ 2
#define NFEAT 43   // 20 sortedX + 20 sortedY + 2 coords + 1 bias

// ---------------------------------------------------------------------------
// Kernel A: build the fused affine map M[43][128].
//   out[b,n,g] = sum_r feat[b,n,r] * M[r][g]
//   feat = [sortedX flat (k*2+c), sortedY flat, x, y, 1]
//   rows 0..19 : M[k*2+c][g] = sum_h Wx[h,c,k] * W2[h,g]
//   rows 20..39: same with Wy
//   rows 40..41: W1[c][g]
//   row  42    : sum_h (bx+by)[h]*W2[h,g] + b1[g] + b2[g]
// ---------------------------------------------------------------------------
__global__ __launch_bounds__(H_) void build_meff(
    const float* __restrict__ Wx, const float* __restrict__ bx,
    const float* __restrict__ Wy, const float* __restrict__ by,
    const float* __restrict__ W1, const float* __restrict__ b1,
    const float* __restrict__ W2, const float* __restrict__ b2,
    float* __restrict__ M) {
  const int r = blockIdx.x;
  const int g = threadIdx.x;
  float acc = 0.f;
  if (r < 40) {
    const int rp = (r < 20) ? r : r - 20;
    const float* W = (r < 20) ? Wx : Wy;
    const int k = rp >> 1;
    const int c = rp & 1;
    const float* Wcol = W + c * K_ + k;     // stride H dimension = C_*K_
    for (int h = 0; h < H_; ++h)
      acc = fmaf(Wcol[h * C_ * K_], W2[h * H_ + g], acc);
  } else if (r < 42) {
    acc = W1[(r - 40) * H_ + g];
  } else {
    for (int h = 0; h < H_; ++h)
      acc = fmaf(bx[h] + by[h], W2[h * H_ + g], acc);
    acc += b1[g] + b2[g];
  }
  M[r * H_ + g] = acc;
}

// ---------------------------------------------------------------------------
// Kernel B: per-query KNN + stable coordinate sorts + fused affine output.
// grid = (8 chunks of 128 queries, 32 batches), block = 128 threads.
// ---------------------------------------------------------------------------
__global__ __launch_bounds__(128) void conv_emb_main(
    const float* __restrict__ x, const float* __restrict__ Meff,
    float* __restrict__ out) {
  __shared__ float2 pts[N_];          // 8 KB: this batch's points
  __shared__ float  M[NFEAT * H_];    // 22 KB: fused matrix

  const int b   = blockIdx.y;
  const int tid = threadIdx.x;

  const float2* xb = (const float2*)(x + (size_t)b * N_ * C_);
  for (int i = tid; i < N_; i += 128) pts[i] = xb[i];
  for (int i = tid; i < NFEAT * H_; i += 128) M[i] = Meff[i];
  __syncthreads();

  const int n = blockIdx.x * 128 + tid;
  if (n >= N_) return;

  const float px = pts[n].x;
  const float py = pts[n].y;

  // ---- top-K smallest d2, ties -> lower index (matches lax.top_k) ----
  float bd[K_];
  int   bi[K_];
#pragma unroll
  for (int k = 0; k < K_; ++k) { bd[k] = 3.4e38f; bi[k] = 0; }

#pragma unroll 2
  for (int j = 0; j < N_; ++j) {
    const float2 q = pts[j];
    // match reference rounding: (dx*dx) + (dy*dy), each step rounded, no FMA
    const float dx = __fsub_rn(px, q.x);
    const float dy = __fsub_rn(py, q.y);
    const float d  = __fadd_rn(__fmul_rn(dx, dx), __fmul_rn(dy, dy));
    if (d < bd[K_ - 1]) {               // strict: scanning ascending j => stable
      bd[K_ - 1] = d; bi[K_ - 1] = j;
#pragma unroll
      for (int s = K_ - 1; s > 0; --s) {
        const bool sw = bd[s] < bd[s - 1];     // strict => stable
        const float td = sw ? bd[s - 1] : bd[s];
        const int   ti = sw ? bi[s - 1] : bi[s];
        bd[s - 1] = sw ? bd[s] : bd[s - 1];
        bi[s - 1] = sw ? bi[s] : bi[s - 1];
        bd[s] = td; bi[s] = ti;
      }
    }
  }

  // ---- gather neighbor coords (in ascending-distance order) ----
  float cx1[K_], cy1[K_], cx2[K_], cy2[K_];
#pragma unroll
  for (int k = 0; k < K_; ++k) {
    const float2 c = pts[bi[k]];
    cx1[k] = c.x; cy1[k] = c.y;
    cx2[k] = c.x; cy2[k] = c.y;
  }

  // ---- stable bubble sort by x-coordinate (strict adjacent swap = stable) ----
#pragma unroll
  for (int p = 0; p < K_ - 1; ++p) {
#pragma unroll
    for (int q2 = 0; q2 < K_ - 1 - p; ++q2) {
      const bool sw = cx1[q2 + 1] < cx1[q2];
      const float tx = sw ? cx1[q2] : cx1[q2 + 1];
      const float ty = sw ? cy1[q2] : cy1[q2 + 1];
      cx1[q2]     = sw ? cx1[q2 + 1] : cx1[q2];
      cy1[q2]     = sw ? cy1[q2 + 1] : cy1[q2];
      cx1[q2 + 1] = tx; cy1[q2 + 1] = ty;
    }
  }
  // ---- stable bubble sort by y-coordinate ----
#pragma unroll
  for (int p = 0; p < K_ - 1; ++p) {
#pragma unroll
    for (int q2 = 0; q2 < K_ - 1 - p; ++q2) {
      const bool sw = cy2[q2 + 1] < cy2[q2];
      const float tx = sw ? cx2[q2] : cx2[q2 + 1];
      const float ty = sw ? cy2[q2] : cy2[q2 + 1];
      cx2[q2]     = sw ? cx2[q2 + 1] : cx2[q2];
      cy2[q2]     = sw ? cy2[q2 + 1] : cy2[q2];
      cx2[q2 + 1] = tx; cy2[q2 + 1] = ty;
    }
  }

  // ---- feature vector ----
  float feat[NFEAT];
#pragma unroll
  for (int k = 0; k < K_; ++k) {
    feat[2 * k]          = cx1[k];
    feat[2 * k + 1]      = cy1[k];
    feat[20 + 2 * k]     = cx2[k];
    feat[20 + 2 * k + 1] = cy2[k];
  }
  feat[40] = px;
  feat[41] = py;
  feat[42] = 1.f;

  // ---- fused affine: out[b,n,g] = feat . M[:,g]  (LDS broadcast reads) ----
  float* op = out + ((size_t)(b * N_ + n)) * H_;
#pragma unroll 4
  for (int g = 0; g < H_; ++g) {
    float acc = 0.f;
#pragma unroll
    for (int r = 0; r < NFEAT; ++r)
      acc = fmaf(feat[r], M[r * H_ + g], acc);
    op[g] = acc;
  }
}

extern "C" void kernel_launch(void* const* d_in, const int* in_sizes, int n_in,
                              void* d_out, int out_size, void* d_ws, size_t ws_size,
                              hipStream_t stream) {
  const float* x  = (const float*)d_in[0];
  const float* Wx = (const float*)d_in[1];
  const float* bx = (const float*)d_in[2];
  const float* Wy = (const float*)d_in[3];
  const float* by = (const float*)d_in[4];
  const float* W1 = (const float*)d_in[5];
  const float* b1 = (const float*)d_in[6];
  const float* W2 = (const float*)d_in[7];
  const float* b2 = (const float*)d_in[8];
  float* out  = (float*)d_out;
  float* Meff = (float*)d_ws;   // 43*128 floats = 22 KB

  build_meff<<<dim3(NFEAT), dim3(H_), 0, stream>>>(Wx, bx, Wy, by, W1, b1, W2, b2, Meff);
  conv_emb_main<<<dim3(8, B_), dim3(128), 0, stream>>>(x, Meff, out);
}

// Round 2
// 84.565 us; speedup vs baseline: 10.3465x; 10.3465x over previous
//
#include <hip/hip_runtime.h>
#include <cfloat>

#define B_ 32
#define N_ 1000
#define K_ 10
#define H_ 128
#define C_ 2
#define NFEAT 43    // 20 sortedX + 20 sortedY + 2 coords + 1 bias
#define QPB 32      // queries per block
#define TPQ 8       // threads per query
#define NCAND (N_ / TPQ)   // 125 candidates per thread
#define LSTRIDE 170 // floats per query's merge-list region (padded: 170%32=10 -> distinct banks across queries)

// ---------------------------------------------------------------------------
// Kernel A: build the fused affine map M[43][128] (folds Wx,Wy,W1,W2,biases).
// ---------------------------------------------------------------------------
__global__ __launch_bounds__(H_) void build_meff(
    const float* __restrict__ Wx, const float* __restrict__ bx,
    const float* __restrict__ Wy, const float* __restrict__ by,
    const float* __restrict__ W1, const float* __restrict__ b1,
    const float* __restrict__ W2, const float* __restrict__ b2,
    float* __restrict__ M) {
  const int r = blockIdx.x;
  const int g = threadIdx.x;
  float acc = 0.f;
  if (r < 40) {
    const int rp = (r < 20) ? r : r - 20;
    const float* W = (r < 20) ? Wx : Wy;
    const int k = rp >> 1;
    const int c = rp & 1;
    const float* Wcol = W + c * K_ + k;     // h-stride = C_*K_
    for (int h = 0; h < H_; ++h)
      acc = fmaf(Wcol[h * C_ * K_], W2[h * H_ + g], acc);
  } else if (r < 42) {
    acc = W1[(r - 40) * H_ + g];
  } else {
    for (int h = 0; h < H_; ++h)
      acc = fmaf(bx[h] + by[h], W2[h * H_ + g], acc);
    acc += b1[g] + b2[g];
  }
  M[r * H_ + g] = acc;
}

// ---------------------------------------------------------------------------
// Kernel B: 8 threads/query. Sliced KNN scan (branchless rank-insert) ->
// LDS 8-way merge with (d, idx) tie-break -> stable coord sorts -> fused affine.
// grid = (32 query-chunks, 32 batches), block = 256.
// ---------------------------------------------------------------------------
__global__ __launch_bounds__(QPB * TPQ, 4) void conv_emb_main(
    const float* __restrict__ x, const float* __restrict__ Meff,
    float* __restrict__ out) {
  __shared__ float2 pts[N_];            // 8 KB
  __shared__ float  smem[NFEAT * H_];   // 22 KB: merge scratch, later M (5504 >= 32*170=5440)
  __shared__ int    midx[QPB * K_];     // 1.25 KB merged indices

  const int b   = blockIdx.y;
  const int tid = threadIdx.x;
  const int q   = tid >> 3;             // local query 0..31
  const int t   = tid & 7;              // slice id 0..7
  const int n   = blockIdx.x * QPB + q;
  const bool valid = (n < N_);

  const float2* xb = (const float2*)(x + (size_t)b * N_ * C_);
  for (int i = tid; i < N_; i += QPB * TPQ) pts[i] = xb[i];
  __syncthreads();

  float px = 0.f, py = 0.f;
  if (valid) { px = pts[n].x; py = pts[n].y; }

  // ---- per-thread top-10 of slice j = t, t+8, ... (ascending idx => stable) ----
  float bd[K_]; int bi[K_];
#pragma unroll
  for (int k = 0; k < K_; ++k) { bd[k] = FLT_MAX; bi[k] = 0; }

#pragma unroll 2
  for (int m = 0; m < NCAND; ++m) {
    const int j = t + m * TPQ;
    const float2 p = pts[j];
    // reference rounding: dx*dx + dy*dy, each step rounded, no FMA
    const float dx = __fsub_rn(px, p.x);
    const float dy = __fsub_rn(py, p.y);
    const float d  = __fadd_rn(__fmul_rn(dx, dx), __fmul_rn(dy, dy));
    // branchless rank insert: pos = first s with d < bd[s] (strict => ties keep lower idx)
    bool c[K_];
#pragma unroll
    for (int s = 0; s < K_; ++s) c[s] = d < bd[s];
#pragma unroll
    for (int s = K_ - 1; s >= 1; --s) {
      bd[s] = c[s - 1] ? bd[s - 1] : (c[s] ? d : bd[s]);
      bi[s] = c[s - 1] ? bi[s - 1] : (c[s] ? j : bi[s]);
    }
    bd[0] = c[0] ? d : bd[0];
    bi[0] = c[0] ? j : bi[0];
  }

  // ---- publish sorted slice lists to LDS ----
  const int lbase = q * LSTRIDE + t * 2 * K_;
#pragma unroll
  for (int e = 0; e < K_; ++e) {
    smem[lbase + 2 * e]     = bd[e];
    smem[lbase + 2 * e + 1] = __int_as_float(bi[e]);
  }
  __syncthreads();

  // ---- 8-way merge (lane t==0 of each query), lex (d, idx) => top_k semantics ----
  if (t == 0 && valid) {
    int cc[TPQ];
#pragma unroll
    for (int tt = 0; tt < TPQ; ++tt) cc[tt] = 0;
    const int mb = q * LSTRIDE;
#pragma unroll
    for (int s = 0; s < K_; ++s) {
      float bdv = FLT_MAX; int biv = 0x7fffffff; int bt = 0;
#pragma unroll
      for (int tt = 0; tt < TPQ; ++tt) {
        const int off = mb + tt * 2 * K_ + cc[tt] * 2;
        const float hd = smem[off];
        const int   hi = __float_as_int(smem[off + 1]);
        const bool take = (hd < bdv) || ((hd == bdv) && (hi < biv));
        bdv = take ? hd : bdv;
        biv = take ? hi : biv;
        bt  = take ? tt : bt;
      }
      midx[q * K_ + s] = biv;
#pragma unroll
      for (int tt = 0; tt < TPQ; ++tt) cc[tt] += (bt == tt) ? 1 : 0;
    }
  }
  __syncthreads();

  // ---- read merged indices, then repurpose smem for M ----
  int ridx[K_];
  if (valid) {
#pragma unroll
    for (int k = 0; k < K_; ++k) ridx[k] = midx[q * K_ + k];
  }
  for (int i = tid; i < NFEAT * H_; i += QPB * TPQ) smem[i] = Meff[i];

  // ---- gather coords + stable bubble sorts (redundant across 8 threads; lanes were idle) ----
  float feat[NFEAT];
  if (valid) {
    float cx1[K_], cy1[K_], cx2[K_], cy2[K_];
#pragma unroll
    for (int k = 0; k < K_; ++k) {
      const float2 c = pts[ridx[k]];
      cx1[k] = c.x; cy1[k] = c.y;
      cx2[k] = c.x; cy2[k] = c.y;
    }
#pragma unroll
    for (int p = 0; p < K_ - 1; ++p) {
#pragma unroll
      for (int s = 0; s < K_ - 1 - p; ++s) {
        const bool sw = cx1[s + 1] < cx1[s];   // strict => stable
        const float tx = sw ? cx1[s] : cx1[s + 1];
        const float ty = sw ? cy1[s] : cy1[s + 1];
        cx1[s]     = sw ? cx1[s + 1] : cx1[s];
        cy1[s]     = sw ? cy1[s + 1] : cy1[s];
        cx1[s + 1] = tx; cy1[s + 1] = ty;
      }
    }
#pragma unroll
    for (int p = 0; p < K_ - 1; ++p) {
#pragma unroll
      for (int s = 0; s < K_ - 1 - p; ++s) {
        const bool sw = cy2[s + 1] < cy2[s];
        const float tx = sw ? cx2[s] : cx2[s + 1];
        const float ty = sw ? cy2[s] : cy2[s + 1];
        cx2[s]     = sw ? cx2[s + 1] : cx2[s];
        cy2[s]     = sw ? cy2[s + 1] : cy2[s];
        cx2[s + 1] = tx; cy2[s + 1] = ty;
      }
    }
#pragma unroll
    for (int k = 0; k < K_; ++k) {
      feat[2 * k]          = cx1[k];
      feat[2 * k + 1]      = cy1[k];
      feat[20 + 2 * k]     = cx2[k];
      feat[20 + 2 * k + 1] = cy2[k];
    }
    feat[40] = px;
    feat[41] = py;
    feat[42] = 1.f;
  }
  __syncthreads();

  // ---- fused affine: each thread does 16 outputs, g = gi*8 + t (bank-conflict-free M reads) ----
  if (valid) {
    float* op = out + ((size_t)(b * N_ + n)) * H_;
#pragma unroll 2
    for (int gi = 0; gi < H_ / TPQ; ++gi) {
      const int g = gi * TPQ + t;
      float acc = 0.f;
#pragma unroll
      for (int r = 0; r < NFEAT; ++r)
        acc = fmaf(feat[r], smem[r * H_ + g], acc);
      op[g] = acc;
    }
  }
}

extern "C" void kernel_launch(void* const* d_in, const int* in_sizes, int n_in,
                              void* d_out, int out_size, void* d_ws, size_t ws_size,
                              hipStream_t stream) {
  const float* x  = (const float*)d_in[0];
  const float* Wx = (const float*)d_in[1];
  const float* bx = (const float*)d_in[2];
  const float* Wy = (const float*)d_in[3];
  const float* by = (const float*)d_in[4];
  const float* W1 = (const float*)d_in[5];
  const float* b1 = (const float*)d_in[6];
  const float* W2 = (const float*)d_in[7];
  const float* b2 = (const float*)d_in[8];
  float* o    = (float*)d_out;
  float* Meff = (float*)d_ws;   // 43*128 floats

  build_meff<<<dim3(NFEAT), dim3(H_), 0, stream>>>(Wx, bx, Wy, by, W1, b1, W2, b2, Meff);
  conv_emb_main<<<dim3((N_ + QPB - 1) / QPB, B_), dim3(QPB * TPQ), 0, stream>>>(x, Meff, o);
}